// Round 1
// baseline (357.072 us; speedup 1.0000x reference)
//
#include <hip/hip_runtime.h>

#define B_    2
#define CE_   32
#define D_    12
#define H_    256
#define W_    256
#define HW_   (H_*W_)
#define HID_  256
#define NPD   8
#define NPH   25
#define NPW   25
#define NP_   10000
#define PJ    1805               // 5*19*19
#define JTP   114                // padded j-tiles (even)
#define MS_   16                 // m-split (grid.y)
#define PB_   313                // gather blocks (32 patches each, covers 10016)

typedef __attribute__((ext_vector_type(8))) short s8v;     // 8 bf16
typedef __attribute__((ext_vector_type(4))) float f32x4;

__device__ __forceinline__ unsigned short f2bf(float f) {
    unsigned u = __float_as_uint(f);
    u += 0x7FFFu + ((u >> 16) & 1u);   // RNE
    return (unsigned short)(u >> 16);
}

__device__ __forceinline__ void decompose_n(int n, int& b, int& pd, int& ph, int& pw) {
    b = n / (NPD*NPH*NPW);
    int r = n - b*(NPD*NPH*NPW);
    pd = r / (NPH*NPW);
    int r2 = r - pd*(NPH*NPW);
    ph = r2 / NPW;
    pw = r2 - ph*NPW;
}

// ---------------- fused staging kernel: 4 independent phases by blockIdx ----
// [0,313)    : emb gather + ballot compaction + GEMM1 -> hA frag-order + meta
//              (longest pole: launched first, 32 patches/block for 2x parallelism)
// [313,427)  : W2 -> W2t bf16 transpose (rows j, padded to 1824)
// 427        : (offj, bj) LUT (1824 entries)
// [428,1196) : 2x2 min/max pack of gt -> M (8 output rows/block)
__global__ __launch_bounds__(256) void k_stage(
    const float* __restrict__ W2, const float* __restrict__ b2,
    const float* __restrict__ target, const float* __restrict__ pred,
    const float* __restrict__ W1, const float* __restrict__ b1,
    unsigned short* __restrict__ W2t, int2* __restrict__ lut,
    unsigned short* __restrict__ M, unsigned short* __restrict__ hA,
    int2* __restrict__ meta, int* __restrict__ cnt)
{
    const int bx = blockIdx.x;
    const int t  = threadIdx.x;

    if (bx < PB_) {
        __shared__ float emb_s[32][36];        // stride 36: float4-aligned rows
        __shared__ int   slot_s[32];
        const int n0 = bx * 32;
        {   // gather: thread (m = t&31, cg = t>>5) loads 4 channels
            const int m = t & 31, cg = t >> 5;
            int n = n0 + m; if (n >= NP_) n = NP_-1;
            int b, pd, ph, pw; decompose_n(n, b, pd, ph, pw);
            const int dc = 2+pd, hc = 21+9*ph, wc = 21+9*pw;
            const size_t base = ((size_t)(b*CE_ + cg*4)*D_ + dc)*HW_ + (size_t)hc*W_ + wc;
            #pragma unroll
            for (int i = 0; i < 4; i++)
                emb_s[m][cg*4+i] = pred[base + (size_t)i*D_*HW_];
        }
        if (t < 32) {   // validity + ballot compaction (1 atomic/block)
            int n = n0 + t; const bool inb = (n < NP_); if (!inb) n = NP_-1;
            int b, pd, ph, pw; decompose_n(n, b, pd, ph, pw);
            const int dc = 2+pd, hc = 21+9*ph, wc = 21+9*pw;
            const size_t tb = ((size_t)(b*4)*D_ + dc)*HW_ + (size_t)hc*W_ + wc;
            const float ctr = target[tb];
            const float a1v = target[tb + (size_t)(1*D_*HW_)];
            const float a2v = target[tb + (size_t)(2*D_*HW_)];
            const float a3v = target[tb + (size_t)(3*D_*HW_)];
            const bool v = inb && (ctr!=0.f) && (a1v!=0.f) && (a2v!=0.f) && (a3v!=0.f);
            const unsigned long long bal = __ballot(v);
            int base = 0;
            if (t == 0) base = atomicAdd(cnt, __popcll(bal));
            base = __shfl(base, 0);
            int s = -1;
            if (v) {
                s = base + (int)__popcll(bal & ((1ull << t) - 1ull));
                const int ci = (int)ctr;
                meta[s] = make_int2((b*D_+pd)*HW_ + (2+9*ph)*W_ + (2+9*pw),
                                    (ci<<8)|ci);
            }
            slot_s[t] = s;
        }
        __syncthreads();
        // GEMM1: thread owns column t
        float wcol[CE_];
        #pragma unroll
        for (int i = 0; i < CE_; i++) wcol[i] = W1[(size_t)i*HID_ + t];
        const float bb = b1[t];
        const int kk = t>>5, quad = (t>>3)&3, e = t&7;
        for (int mm = 0; mm < 32; mm++) {
            const int s = slot_s[mm];          // uniform branch
            if (s < 0) continue;
            float a = bb;
            #pragma unroll
            for (int cc = 0; cc < CE_; cc += 4) {
                const float4 ev = *(const float4*)&emb_s[mm][cc];
                a = fmaf(ev.x, wcol[cc+0], a);
                a = fmaf(ev.y, wcol[cc+1], a);
                a = fmaf(ev.z, wcol[cc+2], a);
                a = fmaf(ev.w, wcol[cc+3], a);
            }
            hA[(size_t)(((s>>4)*8+kk)*4+quad)*128 + (s&15)*8 + e] = f2bf(fmaxf(a, 0.f));
        }
    } else if (bx < PB_ + JTP) {
        __shared__ unsigned short tile[16][264];
        const int j0 = (bx - PB_) * 16;
        const int jj = t & 15, kb = t >> 4;
        #pragma unroll
        for (int ki = 0; ki < 16; ki++) {
            const int k = kb*16 + ki;
            const int j = j0 + jj;
            const float v = (j < PJ) ? W2[(size_t)k*PJ + j] : 0.f;
            tile[jj][k] = f2bf(v);
        }
        __syncthreads();
        const int jr = t >> 4, kc = t & 15;
        s8v a = *(const s8v*)&tile[jr][kc*16];
        s8v b = *(const s8v*)&tile[jr][kc*16+8];
        *(s8v*)&W2t[(size_t)(j0+jr)*HID_ + kc*16]     = a;
        *(s8v*)&W2t[(size_t)(j0+jr)*HID_ + kc*16 + 8] = b;
    } else if (bx == PB_ + JTP) {
        for (int i = t; i < JTP*16; i += 256) {
            int off = 0; float bj = 0.f;
            if (i < PJ) {
                const int dz = i/361, rj = i - dz*361;
                const int yy = rj/19, xx = rj - yy*19;
                off = dz*HW_ + yy*(2*W_) + xx*2;
                bj = b2[i];
            }
            lut[i] = make_int2(off, __float_as_int(bj));
        }
    } else {
        __shared__ float rows[9][256];
        const int bx2 = bx - (PB_ + JTP + 1);  // 0..767
        const int bd = bx2 >> 5;               // b*D+d
        const int h0 = (bx2 & 31) << 3;        // 8 output rows/block
        const int b  = bd / D_, d = bd - b*D_;
        const size_t gbase = ((size_t)(b*4*D_) + d)*HW_;
        #pragma unroll
        for (int r = 0; r < 9; r++) {
            int h = h0 + r; if (h > 255) h = 255;
            rows[r][t] = target[gbase + h*W_ + t];
        }
        __syncthreads();
        const int w1 = (t < 255) ? t+1 : 255;
        #pragma unroll
        for (int r = 0; r < 8; r++) {
            const float g00 = rows[r][t],   g01 = rows[r][w1];
            const float g10 = rows[r+1][t], g11 = rows[r+1][w1];
            const float mn = fminf(fminf(g00,g01), fminf(g10,g11));
            const float mx = fmaxf(fmaxf(g00,g01), fmaxf(g10,g11));
            M[(size_t)bd*HW_ + (h0+r)*W_ + t] = (unsigned short)(((int)mn << 8) | (int)mx);
        }
    }
}

// ---------------- barrier-free MFMA GEMM2 + epilogue + folded finalize ------
// block owns 2 j-tiles (B-frags register-resident); each wave streams m-tiles
__global__ __launch_bounds__(256, 4) void k_main(
    const unsigned short* __restrict__ hA, const unsigned short* __restrict__ W2t,
    const int2* __restrict__ lut, const unsigned short* __restrict__ M,
    const int2* __restrict__ meta, const int* __restrict__ cnt,
    double* __restrict__ accs, unsigned* __restrict__ ticket,
    float* __restrict__ out)
{
    __shared__ float red_s[4][3];
    const int tid  = threadIdx.x;
    const int wv   = tid >> 6;
    const int lane = tid & 63;
    const int quad = lane >> 4;
    const int l16  = lane & 15;
    const int jt0  = blockIdx.x * 2;       // 0..112 (jt0+1 may be pad tile 113)
    const int ms   = blockIdx.y;           // 0..MS_-1
    const int nv   = *cnt;
    const int nmt  = (nv + 15) >> 4;       // active m-tiles

    // resident B fragments for both j-tiles
    s8v bfr0[8], bfr1[8];
    {
        const unsigned short* w0 = W2t + (size_t)(jt0*16 + l16)*HID_ + quad*8;
        const unsigned short* w1 = w0 + 16*HID_;
        #pragma unroll
        for (int kk = 0; kk < 8; kk++) {
            bfr0[kk] = *(const s8v*)(w0 + kk*32);
            bfr1[kk] = *(const s8v*)(w1 + kk*32);
        }
    }
    const int j0 = jt0*16 + l16, j1 = j0 + 16;
    const int2 lb0 = lut[j0], lb1 = lut[j1];
    const bool jok0 = (j0 < PJ), jok1 = (j1 < PJ);
    const float bj0 = __int_as_float(lb0.y), bj1 = __int_as_float(lb1.y);
    const unsigned short* Mp0 = M + lb0.x;
    const unsigned short* Mp1 = M + lb1.x;

    float num = 0.f, denp = 0.f, dent = 0.f;

#define EPI(MB, CPV) do {                                              \
        if (jok0) {                                                    \
            const unsigned mv = Mp0[(MB)];                             \
            if (mv >= 256u) {                                          \
                const float tv = (mv != (CPV)) ? 1.f : 0.f;            \
                const float pv = 1.f / (1.f + __expf(-(a0[r] + bj0))); \
                num  = fmaf(pv, tv, num);                              \
                denp = fmaf(pv, pv, denp);                             \
                dent += tv;                                            \
            }                                                          \
        }                                                              \
        if (jok1) {                                                    \
            const unsigned mv = Mp1[(MB)];                             \
            if (mv >= 256u) {                                          \
                const float tv = (mv != (CPV)) ? 1.f : 0.f;            \
                const float pv = 1.f / (1.f + __expf(-(a1[r] + bj1))); \
                num  = fmaf(pv, tv, num);                              \
                denp = fmaf(pv, pv, denp);                             \
                dent += tv;                                            \
            }                                                          \
        }                                                              \
    } while (0)

    for (int mt = ms*4 + wv; mt < nmt; mt += MS_*4) {
        const unsigned short* arow = hA + (size_t)mt*4096 + quad*128 + l16*8;
        f32x4 a0 = {0.f,0.f,0.f,0.f}, a1 = {0.f,0.f,0.f,0.f};
        #pragma unroll
        for (int kk = 0; kk < 8; kk++) {
            const s8v af = *(const s8v*)(arow + kk*512);
            a0 = __builtin_amdgcn_mfma_f32_16x16x32_bf16(af, bfr0[kk], a0, 0, 0, 0);
            a1 = __builtin_amdgcn_mfma_f32_16x16x32_bf16(af, bfr1[kk], a1, 0, 0, 0);
        }
        if (mt*16 + 16 <= nv) {
            // full tile: no per-p clamp, vector meta load (2 x int4 = 4 int2)
            const int4* mp = (const int4*)(meta + mt*16 + quad*4);
            const int4 u = mp[0], v = mp[1];
            #pragma unroll
            for (int r = 0; r < 4; r++) {
                const int mb = (r==0) ? u.x : (r==1) ? u.z : (r==2) ? v.x : v.z;
                const unsigned cpv = (unsigned)((r==0) ? u.y : (r==1) ? u.w
                                                : (r==2) ? v.y : v.w);
                EPI(mb, cpv);
            }
        } else {
            #pragma unroll
            for (int r = 0; r < 4; r++) {
                const int p = mt*16 + quad*4 + r;
                const bool pok = (p < nv);
                const int2 md = meta[pok ? p : 0];     // clamped: safe mb
                const int mb = md.x;
                const unsigned cpv = (unsigned)md.y;
                if (pok) { EPI(mb, cpv); }
            }
        }
    }
#undef EPI

    // wave reduce, block reduce, spread atomics, last-block finalize
    #pragma unroll
    for (int off = 32; off > 0; off >>= 1) {
        num  += __shfl_down(num,  off);
        denp += __shfl_down(denp, off);
        dent += __shfl_down(dent, off);
    }
    if (lane == 0) { red_s[wv][0] = num; red_s[wv][1] = denp; red_s[wv][2] = dent; }
    __syncthreads();
    if (tid == 0) {
        const float n_ = red_s[0][0]+red_s[1][0]+red_s[2][0]+red_s[3][0];
        const float p_ = red_s[0][1]+red_s[1][1]+red_s[2][1]+red_s[3][1];
        const float t_ = red_s[0][2]+red_s[1][2]+red_s[2][2]+red_s[3][2];
        const int slot = (blockIdx.x + blockIdx.y*57) & 31;
        atomicAdd(&accs[slot*4 + 0], (double)n_);
        atomicAdd(&accs[slot*4 + 1], (double)p_);
        atomicAdd(&accs[slot*4 + 2], (double)t_);
        __threadfence();
        const unsigned done = atomicAdd(ticket, 1u);
        if (done == gridDim.x * gridDim.y - 1u) {
            __threadfence();
            double nn = 0.0, dd = 0.0;
            for (int s2 = 0; s2 < 32; s2++) {
                nn += atomicAdd(&accs[s2*4 + 0], 0.0);
                dd += atomicAdd(&accs[s2*4 + 1], 0.0)
                    + atomicAdd(&accs[s2*4 + 2], 0.0);
            }
            const double d = dd > 1e-6 ? dd : 1e-6;
            out[0] = (float)(-2.0 * nn / d);
        }
    }
}

extern "C" void kernel_launch(void* const* d_in, const int* in_sizes, int n_in,
                              void* d_out, int out_size, void* d_ws, size_t ws_size,
                              hipStream_t stream) {
    const float* target = (const float*)d_in[0];
    const float* pred   = (const float*)d_in[1];
    const float* W1     = (const float*)d_in[2];
    const float* b1     = (const float*)d_in[3];
    const float* W2     = (const float*)d_in[4];
    const float* b2     = (const float*)d_in[5];
    float* out = (float*)d_out;

    char* ws = (char*)d_ws;
    double*         accs   = (double*)ws;                     // 32*4 doubles = 1024 B
    int*            cnt    = (int*)(ws + 1024);
    unsigned*       ticket = (unsigned*)(ws + 1028);
    int2*           meta   = (int2*)(ws + 1056);              // 10048*8 = 80,384 (32B-aligned)
    unsigned short* hA     = (unsigned short*)(ws + 81472);   // 628*4096*2 = 5,144,576
    unsigned short* W2t    = (unsigned short*)(ws + 5226048); // 1824*256*2 = 933,888
    int2*           lut    = (int2*)(ws + 6159936);           // 1824*8 = 14,592
    unsigned short* Mx     = (unsigned short*)(ws + 6174528); // 3,145,728 (end 9,320,256)

    hipMemsetAsync(d_ws, 0, 1056, stream);                    // accs + cnt + ticket
    hipLaunchKernelGGL(k_stage, dim3(1196),    dim3(256), 0, stream,
                       W2, b2, target, pred, W1, b1, W2t, lut, Mx, hA, meta, cnt);
    hipLaunchKernelGGL(k_main,  dim3(57, MS_), dim3(256), 0, stream,
                       hA, W2t, lut, Mx, meta, cnt, accs, ticket, out);
}

// Round 2
// 313.269 us; speedup vs baseline: 1.1398x; 1.1398x over previous
//
#include <hip/hip_runtime.h>

#define B_    2
#define CE_   32
#define D_    12
#define H_    256
#define W_    256
#define HW_   (H_*W_)
#define HID_  256
#define NPD   8
#define NPH   25
#define NPW   25
#define NP_   10000
#define PJ    1805               // 5*19*19
#define JTP   114                // padded j-tiles (even)
#define MS_   16                 // m-split (grid.y)
#define GB_   157                // gather blocks (64 patches each, covers 10048)

typedef __attribute__((ext_vector_type(8))) short s8v;     // 8 bf16
typedef __attribute__((ext_vector_type(4))) float f32x4;

__device__ __forceinline__ unsigned short f2bf(float f) {
    unsigned u = __float_as_uint(f);
    u += 0x7FFFu + ((u >> 16) & 1u);   // RNE
    return (unsigned short)(u >> 16);
}

__device__ __forceinline__ void decompose_n(int n, int& b, int& pd, int& ph, int& pw) {
    b = n / (NPD*NPH*NPW);
    int r = n - b*(NPD*NPH*NPW);
    pd = r / (NPH*NPW);
    int r2 = r - pd*(NPH*NPW);
    ph = r2 / NPW;
    pw = r2 - ph*NPW;
}

// ---------------- fused staging kernel: 4 independent phases by blockIdx ----
// [0,157)    : emb gather + ballot compaction + GEMM1 -> hA frag-order + meta
//              (longest-serial phase: launched first)
// [157,271)  : W2 -> W2t bf16 transpose (rows j, padded to 1824)
// 271        : (offj, bj) LUT (1824 entries)
// [272,1040) : 2x2 min/max pack of gt -> M (8 output rows/block)
__global__ __launch_bounds__(256) void k_stage(
    const float* __restrict__ W2, const float* __restrict__ b2,
    const float* __restrict__ target, const float* __restrict__ pred,
    const float* __restrict__ W1, const float* __restrict__ b1,
    unsigned short* __restrict__ W2t, int2* __restrict__ lut,
    unsigned short* __restrict__ M, unsigned short* __restrict__ hA,
    int2* __restrict__ meta, int* __restrict__ cnt)
{
    const int bx = blockIdx.x;
    const int t  = threadIdx.x;

    if (bx < GB_) {
        __shared__ float emb_s[64][36];        // stride 36: float4-aligned rows
        __shared__ int   slot_s[64];
        const int n0 = bx * 64;
        {   // gather: thread (m = t&63, cg = t>>6) loads 8 channels
            const int m = t & 63, cg = t >> 6;
            int n = n0 + m; if (n >= NP_) n = NP_-1;
            int b, pd, ph, pw; decompose_n(n, b, pd, ph, pw);
            const int dc = 2+pd, hc = 21+9*ph, wc = 21+9*pw;
            const size_t base = ((size_t)(b*CE_ + cg*8)*D_ + dc)*HW_ + (size_t)hc*W_ + wc;
            #pragma unroll
            for (int i = 0; i < 8; i++)
                emb_s[m][cg*8+i] = pred[base + (size_t)i*D_*HW_];
        }
        if (t < 64) {   // wave 0: validity + ballot compaction (1 atomic/block)
            int n = n0 + t; const bool inb = (n < NP_); if (!inb) n = NP_-1;
            int b, pd, ph, pw; decompose_n(n, b, pd, ph, pw);
            const int dc = 2+pd, hc = 21+9*ph, wc = 21+9*pw;
            const size_t tb = ((size_t)(b*4)*D_ + dc)*HW_ + (size_t)hc*W_ + wc;
            const float ctr = target[tb];
            const float a1v = target[tb + (size_t)(1*D_*HW_)];
            const float a2v = target[tb + (size_t)(2*D_*HW_)];
            const float a3v = target[tb + (size_t)(3*D_*HW_)];
            const bool v = inb && (ctr!=0.f) && (a1v!=0.f) && (a2v!=0.f) && (a3v!=0.f);
            const unsigned long long bal = __ballot(v);
            int base = 0;
            if (t == 0) base = atomicAdd(cnt, __popcll(bal));
            base = __shfl(base, 0);
            int s = -1;
            if (v) {
                s = base + (int)__popcll(bal & ((1ull << t) - 1ull));
                const int ci = (int)ctr;
                meta[s] = make_int2((b*D_+pd)*HW_ + (2+9*ph)*W_ + (2+9*pw),
                                    (ci<<8)|ci);
            }
            slot_s[t] = s;
        }
        __syncthreads();
        // GEMM1: thread owns column t
        float wcol[CE_];
        #pragma unroll
        for (int i = 0; i < CE_; i++) wcol[i] = W1[(size_t)i*HID_ + t];
        const float bb = b1[t];
        const int kk = t>>5, quad = (t>>3)&3, e = t&7;
        for (int mm = 0; mm < 64; mm++) {
            const int s = slot_s[mm];          // uniform branch
            if (s < 0) continue;
            float a = bb;
            #pragma unroll
            for (int cc = 0; cc < CE_; cc += 4) {
                const float4 ev = *(const float4*)&emb_s[mm][cc];
                a = fmaf(ev.x, wcol[cc+0], a);
                a = fmaf(ev.y, wcol[cc+1], a);
                a = fmaf(ev.z, wcol[cc+2], a);
                a = fmaf(ev.w, wcol[cc+3], a);
            }
            hA[(size_t)(((s>>4)*8+kk)*4+quad)*128 + (s&15)*8 + e] = f2bf(fmaxf(a, 0.f));
        }
    } else if (bx < GB_ + JTP) {
        __shared__ unsigned short tile[16][264];
        const int j0 = (bx - GB_) * 16;
        const int jj = t & 15, kb = t >> 4;
        #pragma unroll
        for (int ki = 0; ki < 16; ki++) {
            const int k = kb*16 + ki;
            const int j = j0 + jj;
            const float v = (j < PJ) ? W2[(size_t)k*PJ + j] : 0.f;
            tile[jj][k] = f2bf(v);
        }
        __syncthreads();
        const int jr = t >> 4, kc = t & 15;
        s8v a = *(const s8v*)&tile[jr][kc*16];
        s8v b = *(const s8v*)&tile[jr][kc*16+8];
        *(s8v*)&W2t[(size_t)(j0+jr)*HID_ + kc*16]     = a;
        *(s8v*)&W2t[(size_t)(j0+jr)*HID_ + kc*16 + 8] = b;
    } else if (bx == GB_ + JTP) {
        for (int i = t; i < JTP*16; i += 256) {
            int off = 0; float bj = 0.f;
            if (i < PJ) {
                const int dz = i/361, rj = i - dz*361;
                const int yy = rj/19, xx = rj - yy*19;
                off = dz*HW_ + yy*(2*W_) + xx*2;
                bj = b2[i];
            }
            lut[i] = make_int2(off, __float_as_int(bj));
        }
    } else {
        __shared__ float rows[9][256];
        const int bx2 = bx - (GB_ + JTP + 1);  // 0..767
        const int bd = bx2 >> 5;               // b*D+d
        const int h0 = (bx2 & 31) << 3;        // 8 output rows/block
        const int b  = bd / D_, d = bd - b*D_;
        const size_t gbase = ((size_t)(b*4*D_) + d)*HW_;
        #pragma unroll
        for (int r = 0; r < 9; r++) {
            int h = h0 + r; if (h > 255) h = 255;
            rows[r][t] = target[gbase + h*W_ + t];
        }
        __syncthreads();
        const int w1 = (t < 255) ? t+1 : 255;
        #pragma unroll
        for (int r = 0; r < 8; r++) {
            const float g00 = rows[r][t],   g01 = rows[r][w1];
            const float g10 = rows[r+1][t], g11 = rows[r+1][w1];
            const float mn = fminf(fminf(g00,g01), fminf(g10,g11));
            const float mx = fmaxf(fmaxf(g00,g01), fmaxf(g10,g11));
            M[(size_t)bd*HW_ + (h0+r)*W_ + t] = (unsigned short)(((int)mn << 8) | (int)mx);
        }
    }
}

// ---------------- barrier-free MFMA GEMM2 + epilogue ------------------------
// block owns 2 j-tiles (B-frags register-resident); each wave streams m-tiles
__global__ __launch_bounds__(256, 4) void k_main(
    const unsigned short* __restrict__ hA, const unsigned short* __restrict__ W2t,
    const int2* __restrict__ lut, const unsigned short* __restrict__ M,
    const int2* __restrict__ meta, const int* __restrict__ cnt,
    double* __restrict__ accs)
{
    __shared__ float red_s[4][3];
    const int tid  = threadIdx.x;
    const int wv   = tid >> 6;
    const int lane = tid & 63;
    const int quad = lane >> 4;
    const int l16  = lane & 15;
    const int jt0  = blockIdx.x * 2;       // 0..112 (jt0+1 may be pad tile 113)
    const int ms   = blockIdx.y;           // 0..MS_-1
    const int nv   = *cnt;
    const int nmt  = (nv + 15) >> 4;       // active m-tiles

    // resident B fragments for both j-tiles
    s8v bfr0[8], bfr1[8];
    {
        const unsigned short* w0 = W2t + (size_t)(jt0*16 + l16)*HID_ + quad*8;
        const unsigned short* w1 = w0 + 16*HID_;
        #pragma unroll
        for (int kk = 0; kk < 8; kk++) {
            bfr0[kk] = *(const s8v*)(w0 + kk*32);
            bfr1[kk] = *(const s8v*)(w1 + kk*32);
        }
    }
    const int j0 = jt0*16 + l16, j1 = j0 + 16;
    const int2 lb0 = lut[j0], lb1 = lut[j1];
    const bool jok0 = (j0 < PJ), jok1 = (j1 < PJ);
    const float bj0 = __int_as_float(lb0.y), bj1 = __int_as_float(lb1.y);
    const unsigned short* Mp0 = M + lb0.x;
    const unsigned short* Mp1 = M + lb1.x;

    float num = 0.f, denp = 0.f, dent = 0.f;

#define EPI(MB, CPV) do {                                              \
        if (jok0) {                                                    \
            const unsigned mv = Mp0[(MB)];                             \
            if (mv >= 256u) {                                          \
                const float tv = (mv != (CPV)) ? 1.f : 0.f;            \
                const float pv = 1.f / (1.f + __expf(-(a0[r] + bj0))); \
                num  = fmaf(pv, tv, num);                              \
                denp = fmaf(pv, pv, denp);                             \
                dent += tv;                                            \
            }                                                          \
        }                                                              \
        if (jok1) {                                                    \
            const unsigned mv = Mp1[(MB)];                             \
            if (mv >= 256u) {                                          \
                const float tv = (mv != (CPV)) ? 1.f : 0.f;            \
                const float pv = 1.f / (1.f + __expf(-(a1[r] + bj1))); \
                num  = fmaf(pv, tv, num);                              \
                denp = fmaf(pv, pv, denp);                             \
                dent += tv;                                            \
            }                                                          \
        }                                                              \
    } while (0)

    for (int mt = ms*4 + wv; mt < nmt; mt += MS_*4) {
        const unsigned short* arow = hA + (size_t)mt*4096 + quad*128 + l16*8;
        f32x4 a0 = {0.f,0.f,0.f,0.f}, a1 = {0.f,0.f,0.f,0.f};
        #pragma unroll
        for (int kk = 0; kk < 8; kk++) {
            const s8v af = *(const s8v*)(arow + kk*512);
            a0 = __builtin_amdgcn_mfma_f32_16x16x32_bf16(af, bfr0[kk], a0, 0, 0, 0);
            a1 = __builtin_amdgcn_mfma_f32_16x16x32_bf16(af, bfr1[kk], a1, 0, 0, 0);
        }
        if (mt*16 + 16 <= nv) {
            // full tile: no per-p clamp, vector meta load (2 x int4 = 4 int2)
            const int4* mp = (const int4*)(meta + mt*16 + quad*4);
            const int4 u = mp[0], v = mp[1];
            #pragma unroll
            for (int r = 0; r < 4; r++) {
                const int mb = (r==0) ? u.x : (r==1) ? u.z : (r==2) ? v.x : v.z;
                const unsigned cpv = (unsigned)((r==0) ? u.y : (r==1) ? u.w
                                                : (r==2) ? v.y : v.w);
                EPI(mb, cpv);
            }
        } else {
            #pragma unroll
            for (int r = 0; r < 4; r++) {
                const int p = mt*16 + quad*4 + r;
                const bool pok = (p < nv);
                const int2 md = meta[pok ? p : 0];     // clamped: safe mb
                const int mb = md.x;
                const unsigned cpv = (unsigned)md.y;
                if (pok) { EPI(mb, cpv); }
            }
        }
    }
#undef EPI

    // wave reduce, block reduce, spread atomics
    #pragma unroll
    for (int off = 32; off > 0; off >>= 1) {
        num  += __shfl_down(num,  off);
        denp += __shfl_down(denp, off);
        dent += __shfl_down(dent, off);
    }
    if (lane == 0) { red_s[wv][0] = num; red_s[wv][1] = denp; red_s[wv][2] = dent; }
    __syncthreads();
    if (tid == 0) {
        const float n_ = red_s[0][0]+red_s[1][0]+red_s[2][0]+red_s[3][0];
        const float p_ = red_s[0][1]+red_s[1][1]+red_s[2][1]+red_s[3][1];
        const float t_ = red_s[0][2]+red_s[1][2]+red_s[2][2]+red_s[3][2];
        const int slot = (blockIdx.x + blockIdx.y*57) & 31;
        atomicAdd(&accs[slot*4 + 0], (double)n_);
        atomicAdd(&accs[slot*4 + 1], (double)p_);
        atomicAdd(&accs[slot*4 + 2], (double)t_);
    }
}

__global__ void k_final(const double* __restrict__ accs, float* __restrict__ out) {
    double num = 0.0, den = 0.0;
    for (int s = 0; s < 32; s++) {
        num += accs[s*4 + 0];
        den += accs[s*4 + 1] + accs[s*4 + 2];
    }
    const double d = den > 1e-6 ? den : 1e-6;
    out[0] = (float)(-2.0 * num / d);
}

extern "C" void kernel_launch(void* const* d_in, const int* in_sizes, int n_in,
                              void* d_out, int out_size, void* d_ws, size_t ws_size,
                              hipStream_t stream) {
    const float* target = (const float*)d_in[0];
    const float* pred   = (const float*)d_in[1];
    const float* W1     = (const float*)d_in[2];
    const float* b1     = (const float*)d_in[3];
    const float* W2     = (const float*)d_in[4];
    const float* b2     = (const float*)d_in[5];
    float* out = (float*)d_out;

    char* ws = (char*)d_ws;
    double*         accs = (double*)ws;                       // 32*4 doubles = 1024 B
    int*            cnt  = (int*)(ws + 1024);
    int2*           meta = (int2*)(ws + 1056);                // 10048*8 = 80,384 (32B-aligned)
    unsigned short* hA   = (unsigned short*)(ws + 81472);     // 628*4096*2 = 5,144,576
    unsigned short* W2t  = (unsigned short*)(ws + 5226048);   // 1824*256*2 = 933,888
    int2*           lut  = (int2*)(ws + 6159936);             // 1824*8 = 14,592
    unsigned short* Mx   = (unsigned short*)(ws + 6174528);   // 3,145,728 (end 9,320,256)

    hipMemsetAsync(d_ws, 0, 1056, stream);                    // accs + cnt
    hipLaunchKernelGGL(k_stage, dim3(1040),    dim3(256), 0, stream,
                       W2, b2, target, pred, W1, b1, W2t, lut, Mx, hA, meta, cnt);
    hipLaunchKernelGGL(k_main,  dim3(57, MS_), dim3(256), 0, stream,
                       hA, W2t, lut, Mx, meta, cnt, accs);
    hipLaunchKernelGGL(k_final, dim3(1), dim3(1), 0, stream, accs, out);
}